// Round 1
// baseline (9.676 us; speedup 1.0000x reference)
//
#include <hip/hip_runtime.h>
#include <math.h>

#define G_EPS 1e-8f

// One workgroup, 1024 threads: thread tid owns element (b = tid/16, j = tid%16).
// Phases: (1) global min/max of h via wave shuffle + LDS partials,
//         (2) conditional range remap, (3) 16x16 matmul + bias via LDS,
//         (4) Gumbel-sigmoid, (5) per-row top-5 membership via strict-greater
//             rank count (identical tie semantics to soft >= fifth_largest).
__global__ __launch_bounds__(1024) void GumbelLinear_kernel(
    const float* __restrict__ h_in,
    const float* __restrict__ w_p,
    const float* __restrict__ bias,
    const float* __restrict__ U1,
    const float* __restrict__ U2,
    float* __restrict__ out)
{
    __shared__ float h_s[64][16];
    __shared__ float w_s[16][16];
    __shared__ float s_s[64][16];
    __shared__ float wmin_s[16];
    __shared__ float wmax_s[16];
    __shared__ float gmm[2];

    const int tid = threadIdx.x;      // 0..1023
    const int b   = tid >> 4;         // row 0..63
    const int j   = tid & 15;         // col 0..15

    float hv = h_in[tid];
    if (tid < 256) w_s[tid >> 4][tid & 15] = w_p[tid];

    // ---- global min/max over all 1024 h elements ----
    float mn = hv, mx = hv;
    #pragma unroll
    for (int off = 32; off > 0; off >>= 1) {
        mn = fminf(mn, __shfl_down(mn, off));
        mx = fmaxf(mx, __shfl_down(mx, off));
    }
    const int lane = tid & 63;
    const int wid  = tid >> 6;        // 16 waves
    if (lane == 0) { wmin_s[wid] = mn; wmax_s[wid] = mx; }
    __syncthreads();
    if (tid == 0) {
        float m0 = wmin_s[0], m1 = wmax_s[0];
        #pragma unroll
        for (int i = 1; i < 16; ++i) {
            m0 = fminf(m0, wmin_s[i]);
            m1 = fmaxf(m1, wmax_s[i]);
        }
        gmm[0] = m0; gmm[1] = m1;
    }
    __syncthreads();
    const float gmin = gmm[0], gmax = gmm[1];

    // ---- conditional range remap (data-dependent, wave-uniform branch) ----
    if (gmax > 100.0f || gmin < -100.0f) {
        float m = (hv - gmin) / (gmax - gmin) * 0.6f - 0.3f;
        hv = fminf(fmaxf(m, -0.3f), 0.3f);
    }
    h_s[b][j] = hv;
    __syncthreads();

    // ---- mask = h @ w_p + bias ----
    float acc = bias[tid];
    #pragma unroll
    for (int k = 0; k < 16; ++k) acc += h_s[b][k] * w_s[k][j];

    // ---- Gumbel noise difference + sigmoid ----
    const float u1 = U1[tid], u2 = U2[tid];
    const float g1 = -logf(-logf(u1 + G_EPS) + G_EPS);
    const float g2 = -logf(-logf(u2 + G_EPS) + G_EPS);
    const float x  = acc + g1 - g2;          // GUMBEL_TEMP = 1.0
    const float soft = 1.0f / (1.0f + expf(-x));

    s_s[b][j] = soft;
    __syncthreads();

    // ---- top-5 membership: soft >= fifth_largest  <=>  rank(strictly greater) <= 4 ----
    int cnt = 0;
    #pragma unroll
    for (int k = 0; k < 16; ++k) cnt += (s_s[b][k] > soft) ? 1 : 0;

    const float hb = (cnt <= 4) ? 1.0f : 0.0f;
    out[tid] = (hb - soft) + soft;           // matches stop_gradient(hb - soft) + soft
}

extern "C" void kernel_launch(void* const* d_in, const int* in_sizes, int n_in,
                              void* d_out, int out_size, void* d_ws, size_t ws_size,
                              hipStream_t stream) {
    // setup_inputs() order: h, input(unused), w_p, bias, U1, U2 — all float32
    const float* h    = (const float*)d_in[0];
    const float* w_p  = (const float*)d_in[2];
    const float* bias = (const float*)d_in[3];
    const float* U1   = (const float*)d_in[4];
    const float* U2   = (const float*)d_in[5];
    float* out = (float*)d_out;              // 1024 floats

    GumbelLinear_kernel<<<1, 1024, 0, stream>>>(h, w_p, bias, U1, U2, out);
}